// Round 11
// baseline (14.876 us; speedup 1.0000x reference)
//
#include <hip/hip_runtime.h>

typedef float vf4 __attribute__((ext_vector_type(4)));

// Async global->LDS, 16B per lane, wave-uniform LDS base (HW: base + lane*16).
__device__ __forceinline__ void gload_lds16(const void* g, void* l) {
    __builtin_amdgcn_global_load_lds(
        (const __attribute__((address_space(1))) void*)g,
        (__attribute__((address_space(3))) void*)l,
        16, 0, 0);
}

// v9 compute path, unchanged: 6 ds_read_b128 (zero-halo rows, no clamps),
// shfl horizontal halo, 3x3 cross-corr with wr and wr^T, g=|gx|+|gy|.
__device__ __forceinline__ void conv_img(const float* __restrict__ buf,
                                         const float wr[9], int c, int R,
                                         float g[4][4], float& gmn, float& gmx)
{
    vf4 m[6];
#pragma unroll
    for (int k = 0; k < 6; ++k)
        m[k] = *(const vf4*)&buf[(4 * R + k) * 64 + 4 * c];

    float w6[6][6];
#pragma unroll
    for (int k = 0; k < 6; ++k) {
        float lft = __shfl_up(m[k].w, 1, 16);    // lane c-1's col 4c-1
        float rgt = __shfl_down(m[k].x, 1, 16);  // lane c+1's col 4c+4
        w6[k][0] = (c == 0)  ? 0.0f : lft;
        w6[k][1] = m[k].x;
        w6[k][2] = m[k].y;
        w6[k][3] = m[k].z;
        w6[k][4] = m[k].w;
        w6[k][5] = (c == 15) ? 0.0f : rgt;
    }

    gmn = __builtin_inff(); gmx = -__builtin_inff();
#pragma unroll
    for (int i = 0; i < 4; ++i) {
#pragma unroll
        for (int j = 0; j < 4; ++j) {
            float gx = 0.0f, gy = 0.0f;
#pragma unroll
            for (int dr = 0; dr < 3; ++dr) {
#pragma unroll
                for (int dc = 0; dc < 3; ++dc) {
                    const float a = w6[i + dr][j + dc];
                    gx = fmaf(a, wr[dr * 3 + dc], gx);
                    gy = fmaf(a, wr[dc * 3 + dr], gy);
                }
            }
            const float gv = fabsf(gx) + fabsf(gy);
            g[i][j] = gv;
            gmn = fminf(gmn, gv);
            gmx = fmaxf(gmx, gv);
        }
    }
}

// One block per 2 images, 256 threads, double-buffered LDS (33.8 KB -> 4 blk/CU).
// Both images' global_load_lds issue at t=0; counted vmcnt waits + RAW s_barrier
// (no __syncthreads vmcnt(0) drain) keep img1's 16 KB in flight under img0's
// compute/reduce/store -> read stream, write stream, and VALU overlap.
__global__ __launch_bounds__(256) void sobel_v10(
    const float* __restrict__ in,      // (2048,1,64,64)
    const float* __restrict__ weight,  // (1,9)
    const float* __restrict__ wfac_p,  // (1,)
    const float* __restrict__ scale_p, // (1,1)
    float* __restrict__ out)
{
    __shared__ __align__(16) float img[2][66 * 64];   // 2 x 16.9 KB, halo rows 0/65
    __shared__ float smin[2][4], smax[2][4];

    const int tid  = threadIdx.x;
    const int lane = tid & 63;
    const int wv   = tid >> 6;
    const int i0   = blockIdx.x * 2;
    const float* __restrict__ src0 = in + (size_t)i0 * 4096;
    const float* __restrict__ src1 = src0 + 4096;
    float* __restrict__ dst0 = out + (size_t)i0 * 4096;
    float* __restrict__ dst1 = dst0 + 4096;

    // Stage BOTH images now: per wave 8 gload_lds (4 per image), 32 KB in flight.
#pragma unroll
    for (int k = 0; k < 4; ++k) {
        const int ci = wv * 4 + k;
        gload_lds16(src0 + ci * 256 + lane * 4, &img[0][64 + ci * 256]);
    }
#pragma unroll
    for (int k = 0; k < 4; ++k) {
        const int ci = wv * 4 + k;
        gload_lds16(src1 + ci * 256 + lane * 4, &img[1][64 + ci * 256]);
    }
    // Zero halo rows of both buffers.
    if (tid < 64)        { img[0][tid] = 0.0f;                img[1][tid] = 0.0f; }
    else if (tid < 128)  { img[0][65 * 64 + (tid - 64)] = 0.0f;
                           img[1][65 * 64 + (tid - 64)] = 0.0f; }

    // Uniform prep overlaps load latency.
    const float wf = fminf(fmaxf(wfac_p[0], 1.0f), 255.0f);
    float wr[9];
#pragma unroll
    for (int i = 0; i < 9; ++i)
        wr[i] = fminf(fmaxf(weight[i], -1.0f), 1.0f) * wf;
    const float invscale = 1.0f / scale_p[0];

    const int c = tid & 15;
    const int R = tid >> 4;

    // --- barrier A: img0 loads (first 4 of 8) + halo ds_writes done; img1 loads stay in flight ---
    asm volatile("s_waitcnt vmcnt(4) lgkmcnt(0)" ::: "memory");
    __builtin_amdgcn_sched_barrier(0);
    __builtin_amdgcn_s_barrier();

    // ---- img0 compute ----
    float g[4][4];
    float gmn, gmx;
    conv_img(img[0], wr, c, R, g, gmn, gmx);
#pragma unroll
    for (int off = 32; off > 0; off >>= 1) {
        gmn = fminf(gmn, __shfl_xor(gmn, off));
        gmx = fmaxf(gmx, __shfl_xor(gmx, off));
    }
    if (lane == 0) { smin[0][wv] = gmn; smax[0][wv] = gmx; }

    // --- barrier B: smin/smax visible (lgkm only; vmcnt untouched) ---
    asm volatile("s_waitcnt lgkmcnt(0)" ::: "memory");
    __builtin_amdgcn_sched_barrier(0);
    __builtin_amdgcn_s_barrier();

    gmn = fminf(fminf(smin[0][0], smin[0][1]), fminf(smin[0][2], smin[0][3]));
    gmx = fmaxf(fmaxf(smax[0][0], smax[0][1]), fmaxf(smax[0][2], smax[0][3]));
    {
        const float inv = 255.0f / fmaxf(gmx - gmn, 1.0f);
#pragma unroll
        for (int i = 0; i < 4; ++i) {
            vf4 o;
            o.x = floorf((g[i][0] - gmn) * inv) * invscale;
            o.y = floorf((g[i][1] - gmn) * inv) * invscale;
            o.z = floorf((g[i][2] - gmn) * inv) * invscale;
            o.w = floorf((g[i][3] - gmn) * inv) * invscale;
            __builtin_nontemporal_store(o, (vf4*)&dst0[(4 * R + i) * 64 + 4 * c]);
        }
    }

    // --- barrier C: img1 loads done. Loads are OLDER than the 16 stores just
    // issued, vmcnt retires in-order -> outstanding<=16 implies loads retired. ---
    asm volatile("s_waitcnt vmcnt(16)" ::: "memory");
    __builtin_amdgcn_sched_barrier(0);
    __builtin_amdgcn_s_barrier();

    // ---- img1 compute ----
    conv_img(img[1], wr, c, R, g, gmn, gmx);
#pragma unroll
    for (int off = 32; off > 0; off >>= 1) {
        gmn = fminf(gmn, __shfl_xor(gmn, off));
        gmx = fmaxf(gmx, __shfl_xor(gmx, off));
    }
    if (lane == 0) { smin[1][wv] = gmn; smax[1][wv] = gmx; }

    asm volatile("s_waitcnt lgkmcnt(0)" ::: "memory");
    __builtin_amdgcn_sched_barrier(0);
    __builtin_amdgcn_s_barrier();

    gmn = fminf(fminf(smin[1][0], smin[1][1]), fminf(smin[1][2], smin[1][3]));
    gmx = fmaxf(fmaxf(smax[1][0], smax[1][1]), fmaxf(smax[1][2], smax[1][3]));
    {
        const float inv = 255.0f / fmaxf(gmx - gmn, 1.0f);
#pragma unroll
        for (int i = 0; i < 4; ++i) {
            vf4 o;
            o.x = floorf((g[i][0] - gmn) * inv) * invscale;
            o.y = floorf((g[i][1] - gmn) * inv) * invscale;
            o.z = floorf((g[i][2] - gmn) * inv) * invscale;
            o.w = floorf((g[i][3] - gmn) * inv) * invscale;
            __builtin_nontemporal_store(o, (vf4*)&dst1[(4 * R + i) * 64 + 4 * c]);
        }
    }
}

extern "C" void kernel_launch(void* const* d_in, const int* in_sizes, int n_in,
                              void* d_out, int out_size, void* d_ws, size_t ws_size,
                              hipStream_t stream) {
    const float* inp   = (const float*)d_in[0];
    const float* wgt   = (const float*)d_in[1];
    const float* wfac  = (const float*)d_in[2];
    const float* scale = (const float*)d_in[3];
    float* out = (float*)d_out;

    sobel_v10<<<1024, 256, 0, stream>>>(inp, wgt, wfac, scale, out);
}

// Round 12
// 13.590 us; speedup vs baseline: 1.0946x; 1.0946x over previous
//
#include <hip/hip_runtime.h>

typedef float vf4 __attribute__((ext_vector_type(4)));

// Async global->LDS, 16B per lane, wave-uniform LDS base (HW: base + lane*16).
__device__ __forceinline__ void gload_lds16(const void* g, void* l) {
    __builtin_amdgcn_global_load_lds(
        (const __attribute__((address_space(1))) void*)g,
        (__attribute__((address_space(3))) void*)l,
        16, 0, 0);
}

// BEST-KNOWN (R9, 13.53 us): one block per 64x64 image, 256 threads.
// - global_load_lds staging, zero-halo LDS rows (no vertical clamp/mask VALU)
// - conflict-free ds_read_b128 compute reads, shfl horizontal halo
// - NONTEMPORAL stores (normal stores thrash L2 write-allocate: +2.5us, R8)
// Refuted levers (do not retry): LDS-phase serialization (R3), per-wave
// read/write serialization (R6), outstanding-read shortfall (R7),
// counted-vmcnt cross-image pipeline (R10).
__global__ __launch_bounds__(256) void sobel_v11(
    const float* __restrict__ in,      // (2048,1,64,64)
    const float* __restrict__ weight,  // (1,9)
    const float* __restrict__ wfac_p,  // (1,)
    const float* __restrict__ scale_p, // (1,1)
    float* __restrict__ out)
{
    __shared__ __align__(16) float img[66 * 64];   // halo rows 0 and 65, 16.9 KB
    __shared__ float smin[4], smax[4];

    const int tid  = threadIdx.x;
    const int lane = tid & 63;
    const int wv   = tid >> 6;
    const float* __restrict__ src = in + (size_t)blockIdx.x * 4096;
    float* __restrict__ dst = out + (size_t)blockIdx.x * 4096;

    // Stage: 16 chunks of 1 KB; global chunk ci -> lds rows (ci*4+1 ..).
#pragma unroll
    for (int k = 0; k < 4; ++k) {
        const int ci = wv * 4 + k;                       // 0..15
        gload_lds16(src + ci * 256 + lane * 4, &img[64 + ci * 256]);
    }
    // Zero the two halo rows (rows 0 and 65).
    if (tid < 64)        img[tid] = 0.0f;
    else if (tid < 128)  img[65 * 64 + (tid - 64)] = 0.0f;

    // Uniform prep overlaps load latency.
    const float wf = fminf(fmaxf(wfac_p[0], 1.0f), 255.0f);
    float wr[9];
#pragma unroll
    for (int i = 0; i < 9; ++i)
        wr[i] = fminf(fmaxf(weight[i], -1.0f), 1.0f) * wf;
    const float invscale = 1.0f / scale_p[0];

    __syncthreads();   // waits vmcnt (gload_lds) + lgkmcnt (halo writes)

    const int c = tid & 15;   // col block: cols 4c..4c+3
    const int R = tid >> 4;   // row block: rows 4R..4R+3

    // 6 ds_read_b128; lds row = (global row)+1 = 4R+k, no clamp, no mask.
    vf4 m[6];
#pragma unroll
    for (int k = 0; k < 6; ++k)
        m[k] = *(const vf4*)&img[(4 * R + k) * 64 + 4 * c];

    // Window expansion: horizontal halo via intra-16-lane shuffle only.
    float w6[6][6];
#pragma unroll
    for (int k = 0; k < 6; ++k) {
        float lft = __shfl_up(m[k].w, 1, 16);    // lane c-1's col 4c-1
        float rgt = __shfl_down(m[k].x, 1, 16);  // lane c+1's col 4c+4
        w6[k][0] = (c == 0)  ? 0.0f : lft;
        w6[k][1] = m[k].x;
        w6[k][2] = m[k].y;
        w6[k][3] = m[k].z;
        w6[k][4] = m[k].w;
        w6[k][5] = (c == 15) ? 0.0f : rgt;
    }

    // 3x3 cross-correlation with wr and wr^T, g = |gx|+|gy|.
    float g[4][4];
    float gmn = __builtin_inff(), gmx = -__builtin_inff();
#pragma unroll
    for (int i = 0; i < 4; ++i) {
#pragma unroll
        for (int j = 0; j < 4; ++j) {
            float gx = 0.0f, gy = 0.0f;
#pragma unroll
            for (int dr = 0; dr < 3; ++dr) {
#pragma unroll
                for (int dc = 0; dc < 3; ++dc) {
                    const float a = w6[i + dr][j + dc];
                    gx = fmaf(a, wr[dr * 3 + dc], gx);
                    gy = fmaf(a, wr[dc * 3 + dr], gy);
                }
            }
            const float gv = fabsf(gx) + fabsf(gy);
            g[i][j] = gv;
            gmn = fminf(gmn, gv);
            gmx = fmaxf(gmx, gv);
        }
    }

    // Per-image min/max: 64-lane butterfly, then 4 waves via LDS.
#pragma unroll
    for (int off = 32; off > 0; off >>= 1) {
        gmn = fminf(gmn, __shfl_xor(gmn, off));
        gmx = fmaxf(gmx, __shfl_xor(gmx, off));
    }
    if (lane == 0) { smin[wv] = gmn; smax[wv] = gmx; }
    __syncthreads();
    gmn = fminf(fminf(smin[0], smin[1]), fminf(smin[2], smin[3]));
    gmx = fmaxf(fmaxf(smax[0], smax[1]), fmaxf(smax[2], smax[3]));

    const float inv = 255.0f / fmaxf(gmx - gmn, 1.0f);

    // Nontemporal float4 stores (stream past L2; output never re-read).
#pragma unroll
    for (int i = 0; i < 4; ++i) {
        vf4 o;
        o.x = floorf((g[i][0] - gmn) * inv) * invscale;
        o.y = floorf((g[i][1] - gmn) * inv) * invscale;
        o.z = floorf((g[i][2] - gmn) * inv) * invscale;
        o.w = floorf((g[i][3] - gmn) * inv) * invscale;
        __builtin_nontemporal_store(o, (vf4*)&dst[(4 * R + i) * 64 + 4 * c]);
    }
}

extern "C" void kernel_launch(void* const* d_in, const int* in_sizes, int n_in,
                              void* d_out, int out_size, void* d_ws, size_t ws_size,
                              hipStream_t stream) {
    const float* inp   = (const float*)d_in[0];
    const float* wgt   = (const float*)d_in[1];
    const float* wfac  = (const float*)d_in[2];
    const float* scale = (const float*)d_in[3];
    float* out = (float*)d_out;

    sobel_v11<<<2048, 256, 0, stream>>>(inp, wgt, wfac, scale, out);
}